// Round 1
// baseline (896.748 us; speedup 1.0000x reference)
//
#include <hip/hip_runtime.h>
#include <math.h>

// MambaBlock: L == D == 1024, N == 16, K(conv) == 3, all fp32.
// Chain: proj(x2) -> conv1d(3-tap)+silu -> {delta GEMM+softplus, B/C skinny GEMM}
//        -> selective scan -> y @ xg^T -> final proj.
// All GEMMs are VALU-bound fp32 (no fp32 MFMA on CDNA4).

#define LL 1024
#define DD 1024
#define NS 16

__device__ __forceinline__ float silu_f(float x) { return x / (1.f + expf(-x)); }
__device__ __forceinline__ float softplus_f(float x) {
  // = max(x,0) + log1p(exp(-|x|))  (matches jax.nn.softplus)
  return fmaxf(x, 0.f) + log1pf(expf(-fabsf(x)));
}

// C[M,N] = act(A[M,K] @ op(B) + bias)
//   TRB=true : B is [N,K] row-major (op = B^T)   -- inner dim contiguous both sides
//   TRB=false: B is [K,N] row-major (op = B)
// act: 0 none, 1 silu, 2 softplus
// 64x64 tile, 256 threads, 4x4 micro-tile, K-tile 32.
template<bool TRB>
__global__ __launch_bounds__(256) void gemm64(const float* __restrict__ A,
    const float* __restrict__ Bmat, const float* __restrict__ bias,
    float* __restrict__ C, int M, int N, int K, int act)
{
  __shared__ float As[32][68];   // As[kk][row]   (pitch 68 to keep float4 alignment, spread banks)
  __shared__ float Bs[32][68];   // Bs[kk][col]
  const int tid = threadIdx.x;
  const int tx = tid & 15, ty = tid >> 4;
  const int m0 = blockIdx.y * 64, n0 = blockIdx.x * 64;
  float acc[4][4] = {{0.f, 0.f, 0.f, 0.f}, {0.f, 0.f, 0.f, 0.f},
                     {0.f, 0.f, 0.f, 0.f}, {0.f, 0.f, 0.f, 0.f}};

  for (int k0 = 0; k0 < K; k0 += 32) {
    {  // A tile: As[kk][r] = A[(m0+r)*K + k0+kk], transposed store
      const int r  = tid >> 3;         // 0..31
      const int kk = (tid & 7) << 2;   // 0,4,..,28
      const float4 v0 = *(const float4*)&A[(size_t)(m0 + r     ) * K + k0 + kk];
      const float4 v1 = *(const float4*)&A[(size_t)(m0 + r + 32) * K + k0 + kk];
      As[kk+0][r]    = v0.x; As[kk+1][r]    = v0.y; As[kk+2][r]    = v0.z; As[kk+3][r]    = v0.w;
      As[kk+0][r+32] = v1.x; As[kk+1][r+32] = v1.y; As[kk+2][r+32] = v1.z; As[kk+3][r+32] = v1.w;
    }
    if (TRB) {  // Bs[kk][c] = B[(n0+c)*K + k0+kk]
      const int r  = tid >> 3;
      const int kk = (tid & 7) << 2;
      const float4 v0 = *(const float4*)&Bmat[(size_t)(n0 + r     ) * K + k0 + kk];
      const float4 v1 = *(const float4*)&Bmat[(size_t)(n0 + r + 32) * K + k0 + kk];
      Bs[kk+0][r]    = v0.x; Bs[kk+1][r]    = v0.y; Bs[kk+2][r]    = v0.z; Bs[kk+3][r]    = v0.w;
      Bs[kk+0][r+32] = v1.x; Bs[kk+1][r+32] = v1.y; Bs[kk+2][r+32] = v1.z; Bs[kk+3][r+32] = v1.w;
    } else {    // Bs[kk][c] = B[(k0+kk)*N + n0+c], direct float4 store
      const int kk = tid >> 4;         // 0..15
      const int c  = (tid & 15) << 2;  // 0..60
      *(float4*)&Bs[kk     ][c] = *(const float4*)&Bmat[(size_t)(k0 + kk     ) * N + n0 + c];
      *(float4*)&Bs[kk + 16][c] = *(const float4*)&Bmat[(size_t)(k0 + kk + 16) * N + n0 + c];
    }
    __syncthreads();
    #pragma unroll
    for (int kk = 0; kk < 32; ++kk) {
      const float4 a4 = *(const float4*)&As[kk][ty << 2];
      const float4 b4 = *(const float4*)&Bs[kk][tx << 2];
      const float av[4] = {a4.x, a4.y, a4.z, a4.w};
      const float bv[4] = {b4.x, b4.y, b4.z, b4.w};
      #pragma unroll
      for (int i = 0; i < 4; ++i)
        #pragma unroll
        for (int j = 0; j < 4; ++j)
          acc[i][j] = fmaf(av[i], bv[j], acc[i][j]);
    }
    __syncthreads();
  }

  #pragma unroll
  for (int i = 0; i < 4; ++i) {
    const int row = m0 + (ty << 2) + i;
    float v[4];
    #pragma unroll
    for (int j = 0; j < 4; ++j) {
      float t = acc[i][j];
      if (bias) t += bias[n0 + (tx << 2) + j];
      if (act == 1) t = silu_f(t);
      else if (act == 2) t = softplus_f(t);
      v[j] = t;
    }
    float4 o; o.x = v[0]; o.y = v[1]; o.z = v[2]; o.w = v[3];
    *(float4*)&C[(size_t)row * N + n0 + (tx << 2)] = o;
  }
}

// xc[o,w] = silu( sum_{i,k} conv_w[o,i,k] * xm[i, w-1+k] + conv_b[o] )
// conv_w layout [o][i][k] (k fastest). 64x64 output tile, i-tiles of 32.
__global__ __launch_bounds__(256) void conv_silu(const float* __restrict__ xm,
    const float* __restrict__ cw, const float* __restrict__ cb,
    float* __restrict__ xc)
{
  __shared__ float Wt[3][32][68];  // Wt[k][ii][o]
  __shared__ float Xs[32][68];     // Xs[ii][j], j -> w0-1+j, j in 0..65
  const int tid = threadIdx.x;
  const int tx = tid & 15, ty = tid >> 4;
  const int w0 = blockIdx.x * 64, o0 = blockIdx.y * 64;
  float acc[4][4] = {{0.f, 0.f, 0.f, 0.f}, {0.f, 0.f, 0.f, 0.f},
                     {0.f, 0.f, 0.f, 0.f}, {0.f, 0.f, 0.f, 0.f}};

  for (int i0 = 0; i0 < DD; i0 += 32) {
    // Weights: 64 o x 32 ii x 3 k = 6144 elems; consecutive lanes walk (ii,k)
    // within one o-row (96 contiguous floats) -> coalesced-ish streaming.
    for (int e = tid; e < 64 * 96; e += 256) {
      const int o = e / 96;
      const int r = e - o * 96;
      const int ii = r / 3;
      const int k = r - ii * 3;
      Wt[k][ii][o] = cw[(size_t)(o0 + o) * (DD * 3) + (size_t)(i0 + ii) * 3 + k];
    }
    {  // Xs: 32 rows x 66 cols (with zero padding at edges)
      const int ii = tid >> 3;
      const int j0 = tid & 7;
      for (int j = j0; j < 66; j += 8) {
        const int w = w0 - 1 + j;
        Xs[ii][j] = (w >= 0 && w < DD) ? xm[(size_t)(i0 + ii) * DD + w] : 0.f;
      }
    }
    __syncthreads();
    #pragma unroll
    for (int ii = 0; ii < 32; ++ii) {
      float wv[3][4];
      #pragma unroll
      for (int k = 0; k < 3; ++k) {
        const float4 w4 = *(const float4*)&Wt[k][ii][ty << 2];
        wv[k][0] = w4.x; wv[k][1] = w4.y; wv[k][2] = w4.z; wv[k][3] = w4.w;
      }
      float xr[6];
      #pragma unroll
      for (int j = 0; j < 6; ++j) xr[j] = Xs[ii][(tx << 2) + j];
      #pragma unroll
      for (int a = 0; a < 4; ++a)
        #pragma unroll
        for (int b = 0; b < 4; ++b) {
          float s = acc[a][b];
          s = fmaf(wv[0][a], xr[b + 0], s);
          s = fmaf(wv[1][a], xr[b + 1], s);
          s = fmaf(wv[2][a], xr[b + 2], s);
          acc[a][b] = s;
        }
    }
    __syncthreads();
  }

  #pragma unroll
  for (int a = 0; a < 4; ++a) {
    const int o = o0 + (ty << 2) + a;
    const float bias = cb[o];
    float v[4];
    #pragma unroll
    for (int b = 0; b < 4; ++b) v[b] = silu_f(acc[a][b] + bias);
    float4 out; out.x = v[0]; out.y = v[1]; out.z = v[2]; out.w = v[3];
    *(float4*)&xc[(size_t)o * DD + w0 + (tx << 2)] = out;
  }
}

// B[l,n] = xc[l,:] . W_B[:,n];  C[l,n] = xc[l,:] . W_C[:,n]   (N=16 each)
__global__ __launch_bounds__(256) void bc_gemm(const float* __restrict__ xc,
    const float* __restrict__ WB, const float* __restrict__ WC,
    float* __restrict__ Bm, float* __restrict__ Cm)
{
  __shared__ float xs[8][DD];
  const int tid = threadIdx.x;
  const int l0 = blockIdx.x * 8;
  for (int idx = tid; idx < 8 * (DD / 4); idx += 256) {
    const int r = idx >> 8;
    const int c4 = (idx & 255) << 2;
    *(float4*)&xs[r][c4] = *(const float4*)&xc[(size_t)(l0 + r) * DD + c4];
  }
  __syncthreads();
  const int r = tid >> 5;        // 0..7
  const int col = tid & 31;      // 0..31 : 0..15 -> B, 16..31 -> C
  const float* __restrict__ W = (col < 16) ? WB : WC;
  const int n = col & 15;
  float acc = 0.f;
  #pragma unroll 8
  for (int k = 0; k < DD; ++k) acc = fmaf(xs[r][k], W[k * NS + n], acc);
  if (col < 16) Bm[(l0 + r) * NS + n] = acc;
  else          Cm[(l0 + r) * NS + n] = acc;
}

// Selective scan: thread = (d, n); 16 n-lanes per d reduce via shfl_xor.
// h[l] = exp(delta[l,d]*A[d,n]) * h[l-1] + delta[l,d]*xc[l,d]*B[l,n]
// y[l,d] = sum_n h[l] * C[l,n]
__global__ __launch_bounds__(256) void ssm_scan(
    const float* __restrict__ delta, const float* __restrict__ xc,
    const float* __restrict__ Bmat, const float* __restrict__ Cmat,
    const float* __restrict__ A_log, float* __restrict__ y)
{
  const int tid = threadIdx.x;
  const int n = tid & 15;
  const int dl = tid >> 4;               // 0..15
  const int d = blockIdx.x * 16 + dl;
  const float Av = -expf(A_log[d * NS + n]);
  float h = 0.f;
  float da[8], xa[8], ba[8], ca[8];
  float db[8], xb[8], bb[8], cb[8];

#define LOAD8(dv, xv, bv, cv, l0)                              \
  _Pragma("unroll")                                            \
  for (int u = 0; u < 8; ++u) {                                \
    dv[u] = delta[((l0) + u) * DD + d];                        \
    xv[u] = xc[((l0) + u) * DD + d];                           \
    bv[u] = Bmat[((l0) + u) * NS + n];                         \
    cv[u] = Cmat[((l0) + u) * NS + n];                         \
  }

#define STEP8(dv, xv, bv, cv, l0)                              \
  _Pragma("unroll")                                            \
  for (int u = 0; u < 8; ++u) {                                \
    const float abar = expf(dv[u] * Av);                       \
    h = fmaf(abar, h, dv[u] * xv[u] * bv[u]);                  \
    float contrib = h * cv[u];                                 \
    contrib += __shfl_xor(contrib, 1);                         \
    contrib += __shfl_xor(contrib, 2);                         \
    contrib += __shfl_xor(contrib, 4);                         \
    contrib += __shfl_xor(contrib, 8);                         \
    if (n == 0) y[((l0) + u) * DD + d] = contrib;              \
  }

  LOAD8(da, xa, ba, ca, 0);
  for (int l0 = 0; l0 < LL; l0 += 16) {
    LOAD8(db, xb, bb, cb, l0 + 8);
    STEP8(da, xa, ba, ca, l0);
    if (l0 + 16 < LL) { LOAD8(da, xa, ba, ca, l0 + 16); }
    STEP8(db, xb, bb, cb, l0 + 8);
  }
#undef LOAD8
#undef STEP8
}

extern "C" void kernel_launch(void* const* d_in, const int* in_sizes, int n_in,
                              void* d_out, int out_size, void* d_ws, size_t ws_size,
                              hipStream_t stream) {
  const float* x       = (const float*)d_in[0];  // [2, 1024, 1024]
  const float* W_proj  = (const float*)d_in[1];  // [1024, 1024]
  const float* b_proj  = (const float*)d_in[2];  // [1024]
  const float* conv_w  = (const float*)d_in[3];  // [1024, 1024, 3]
  const float* conv_b  = (const float*)d_in[4];  // [1024]
  const float* A_log   = (const float*)d_in[5];  // [1024, 16]
  const float* W_delta = (const float*)d_in[6];  // [1024, 1024]
  const float* W_B     = (const float*)d_in[7];  // [1024, 16]
  const float* W_C     = (const float*)d_in[8];  // [1024, 16]
  float* out = (float*)d_out;                    // [1024, 1024]

  // Workspace layout (floats). Peak ~16.2 MB with aliasing; every buffer is
  // fully written before it is read (0xAA poison is harmless).
  float* ws    = (float*)d_ws;
  float* xm    = ws;                 // [L, D]   (dead after conv -> reused as y)
  float* xg    = ws + (1u << 20);    // [L, D]
  float* xc    = ws + (2u << 20);    // [L, D]
  float* delta = ws + (3u << 20);    // [L, D]   (dead after scan -> reused as out1)
  float* Bm    = ws + (4u << 20);    // [L, 16]
  float* Cm    = Bm + LL * NS;       // [L, 16]
  float* yb    = xm;                 // alias
  float* out1  = delta;              // alias

  const dim3 blk(256);
  const dim3 g16(16, 16);

  // p = x @ W_proj^T + b_proj ; xm = p[0], xg = silu(p[1])
  gemm64<true><<<g16, blk, 0, stream>>>(x,             W_proj, b_proj, xm, LL, DD, DD, 0);
  gemm64<true><<<g16, blk, 0, stream>>>(x + (1u << 20), W_proj, b_proj, xg, LL, DD, DD, 1);
  // xc = silu(conv1d(xm))
  conv_silu<<<g16, blk, 0, stream>>>(xm, conv_w, conv_b, xc);
  // delta = softplus(xc @ W_delta)
  gemm64<false><<<g16, blk, 0, stream>>>(xc, W_delta, nullptr, delta, LL, DD, DD, 2);
  // B, C skinny GEMMs
  bc_gemm<<<dim3(128), blk, 0, stream>>>(xc, W_B, W_C, Bm, Cm);
  // selective scan -> y
  ssm_scan<<<dim3(64), blk, 0, stream>>>(delta, xc, Bm, Cm, A_log, yb);
  // out1 = y @ xg^T
  gemm64<true><<<g16, blk, 0, stream>>>(yb, xg, nullptr, out1, LL, LL, DD, 0);
  // out = out1 @ W_proj^T + b_proj
  gemm64<true><<<g16, blk, 0, stream>>>(out1, W_proj, b_proj, out, LL, LL, LL, 0);
}

// Round 3
// 524.102 us; speedup vs baseline: 1.7110x; 1.7110x over previous
//
#include <hip/hip_runtime.h>
#include <math.h>

// MambaBlock on MI355X: all dense contractions via bf16 MFMA (16x16x32),
// fp32 accumulate. L == D == 1024, N == 16, K(conv) == 3.
// GEMM tile 128x NC(=64): grid >=128 blocks at N=1024 (CU utilization).

#define LL 1024
#define DD 1024
#define NS 16

typedef short     bf16x8_t __attribute__((ext_vector_type(8)));
typedef float     f32x4_t  __attribute__((ext_vector_type(4)));
typedef unsigned short u16x4_t __attribute__((ext_vector_type(4)));
typedef unsigned short u16x8_t __attribute__((ext_vector_type(8)));

__device__ __forceinline__ float silu_f(float x) { return x / (1.f + expf(-x)); }
__device__ __forceinline__ float softplus_f(float x) {
  return fmaxf(x, 0.f) + log1pf(expf(-fabsf(x)));
}
__device__ __forceinline__ unsigned short f2bf(float f) {  // RNE
  unsigned int u = __float_as_uint(f);
  u += 0x7fffu + ((u >> 16) & 1u);
  return (unsigned short)(u >> 16);
}

// ---------------- small conversion kernels ----------------
__global__ __launch_bounds__(256) void castk(const float* __restrict__ in,
                                             unsigned short* __restrict__ out, int n) {
  int i = (blockIdx.x * 256 + threadIdx.x) * 4;
  if (i >= n) return;
  float4 v = *(const float4*)(in + i);
  u16x4_t o; o[0] = f2bf(v.x); o[1] = f2bf(v.y); o[2] = f2bf(v.z); o[3] = f2bf(v.w);
  *(u16x4_t*)(out + i) = o;
}

// out[d][k] = W[k][d]  (1024x1024), fp32 -> bf16
__global__ __launch_bounds__(256) void tcastk(const float* __restrict__ W,
                                              unsigned short* __restrict__ out) {
  __shared__ float T[64][65];
  const int t = threadIdx.x;
  const int r = t >> 2, cq = (t & 3) << 4;
  const int d0 = blockIdx.x * 64, k0 = blockIdx.y * 64;
  #pragma unroll
  for (int c = 0; c < 16; c += 4) {
    float4 v = *(const float4*)&W[(size_t)(k0 + r) * DD + d0 + cq + c];
    T[r][cq + c + 0] = v.x; T[r][cq + c + 1] = v.y;
    T[r][cq + c + 2] = v.z; T[r][cq + c + 3] = v.w;
  }
  __syncthreads();
  u16x8_t o0, o1;
  #pragma unroll
  for (int j = 0; j < 8; ++j) o0[j] = f2bf(T[cq + j][r]);
  #pragma unroll
  for (int j = 0; j < 8; ++j) o1[j] = f2bf(T[cq + 8 + j][r]);
  *(u16x8_t*)&out[(size_t)(d0 + r) * DD + k0 + cq] = o0;
  *(u16x8_t*)&out[(size_t)(d0 + r) * DD + k0 + cq + 8] = o1;
}

// XshT[w][i*3+k] = xm[i][w-1+k] (zero-padded), bf16 -> bf16. out is [1024][3072].
__global__ __launch_bounds__(256) void build_xsht(const unsigned short* __restrict__ xm,
                                                  unsigned short* __restrict__ out) {
  __shared__ unsigned short Xs[64][66];
  const int t = threadIdx.x;
  const int w0 = blockIdx.x * 64, i0 = blockIdx.y * 64;
  {
    const int r = t >> 2, cq = (t & 3) << 4;
    #pragma unroll
    for (int c = 0; c < 16; c += 4) {
      u16x4_t v = *(const u16x4_t*)&xm[(size_t)(i0 + r) * DD + w0 + cq + c];
      Xs[r][1 + cq + c + 0] = v[0]; Xs[r][1 + cq + c + 1] = v[1];
      Xs[r][1 + cq + c + 2] = v[2]; Xs[r][1 + cq + c + 3] = v[3];
    }
  }
  if (t < 64)                 Xs[t][0]       = (w0 > 0)        ? xm[(size_t)(i0 + t) * DD + w0 - 1]  : (unsigned short)0;
  else if (t < 128) { int r = t - 64; Xs[r][65] = (w0 + 64 < DD) ? xm[(size_t)(i0 + r) * DD + w0 + 64] : (unsigned short)0; }
  __syncthreads();
  const int wr = t >> 2, q = t & 3;
  unsigned short vals[48];
  #pragma unroll
  for (int ii = 0; ii < 16; ++ii)
    #pragma unroll
    for (int k = 0; k < 3; ++k)
      vals[ii * 3 + k] = Xs[q * 16 + ii][wr + k];
  #pragma unroll
  for (int s = 0; s < 6; ++s) {
    u16x8_t o;
    #pragma unroll
    for (int j = 0; j < 8; ++j) o[j] = vals[s * 8 + j];
    *(u16x8_t*)&out[(size_t)(w0 + wr) * 3072 + (size_t)i0 * 3 + q * 48 + s * 8] = o;
  }
}

// ---------------- bf16 MFMA GEMM: C = act(A[M,K] @ B[N,K]^T + bias) ----------------
// Tile 128 x NC, BK=32, 4 waves (2x2); wave = 64 x NC/2 (4 x NC/32 fragments).
// A and B staged into one LDS array via global_load_lds 16B chunks, linear dest,
// XOR chunk swizzle applied identically on source and read (involution).
// ACT: 0 none, 1 silu, 2 softplus, 3 silu iff row>=1024. BROW: bias by row.
template<int NC, int ACT, bool BROW, bool O32, bool O16>
__global__ __launch_bounds__(256) void gemm_bf16(
    const unsigned short* __restrict__ A, const unsigned short* __restrict__ B,
    const float* __restrict__ bias, float* __restrict__ C32,
    unsigned short* __restrict__ C16, int M, int N, int K)
{
  constexpr int NFR = NC / 32;            // B fragments per wave
  constexpr int TCH = (128 + NC) * 4;     // 16B chunks per K-step (A then B)
  __shared__ unsigned short s[(128 + NC) * 32];
  const int tid  = threadIdx.x;
  const int lane = tid & 63;
  const int wv   = tid >> 6;
  const int wm   = wv >> 1, wn = wv & 1;
  const int m0 = blockIdx.y * 128, n0 = blockIdx.x * NC;
  const int wbase = tid & 192;  // wave-uniform

  f32x4_t acc[4][NFR];
  #pragma unroll
  for (int i = 0; i < 4; ++i)
    #pragma unroll
    for (int j = 0; j < NFR; ++j)
      acc[i][j] = (f32x4_t)(0.f);

  for (int k0 = 0; k0 < K; k0 += 32) {
    #pragma unroll
    for (int it = 0; it < TCH / 256; ++it) {
      const int c   = (it << 8) + tid;          // linear dest chunk id
      const bool isA = (c < 512);
      const int idx = isA ? c : c - 512;
      const int r   = idx >> 2;
      const int kcg = (idx & 3) ^ ((r >> 1) & 3);  // pre-swizzled source k-chunk
      const unsigned short* src = isA ? (A + (size_t)(m0 + r) * K + k0 + kcg * 8)
                                      : (B + (size_t)(n0 + r) * K + k0 + kcg * 8);
      __builtin_amdgcn_global_load_lds(
          (const __attribute__((address_space(1))) void*)src,
          (__attribute__((address_space(3))) void*)(s + (size_t)((it << 8) + wbase) * 8),
          16, 0, 0);
    }
    __syncthreads();

    const int rl = lane & 15, kc = lane >> 4;
    bf16x8_t af[4], bfr[NFR];
    #pragma unroll
    for (int mi = 0; mi < 4; ++mi) {
      const int row = wm * 64 + mi * 16 + rl;
      const int ch  = (row << 2) + (kc ^ ((row >> 1) & 3));
      af[mi] = *(const bf16x8_t*)(s + (size_t)ch * 8);
    }
    #pragma unroll
    for (int ni = 0; ni < NFR; ++ni) {
      const int col = wn * (NC / 2) + ni * 16 + rl;
      const int ch  = 512 + (col << 2) + (kc ^ ((col >> 1) & 3));
      bfr[ni] = *(const bf16x8_t*)(s + (size_t)ch * 8);
    }
    #pragma unroll
    for (int mi = 0; mi < 4; ++mi)
      #pragma unroll
      for (int ni = 0; ni < NFR; ++ni)
        acc[mi][ni] = __builtin_amdgcn_mfma_f32_16x16x32_bf16(af[mi], bfr[ni], acc[mi][ni], 0, 0, 0);
    __syncthreads();
  }

  const int rl = lane & 15, rg = lane >> 4;
  #pragma unroll
  for (int mi = 0; mi < 4; ++mi) {
    #pragma unroll
    for (int ni = 0; ni < NFR; ++ni) {
      const int col = n0 + wn * (NC / 2) + ni * 16 + rl;
      #pragma unroll
      for (int j = 0; j < 4; ++j) {
        const int row = m0 + wm * 64 + mi * 16 + rg * 4 + j;
        float v = acc[mi][ni][j];
        if (bias) v += BROW ? bias[row] : bias[col];
        if (ACT == 1) v = silu_f(v);
        else if (ACT == 2) v = softplus_f(v);
        else if (ACT == 3) { if (row >= 1024) v = silu_f(v); }
        if (O32) C32[(size_t)row * N + col] = v;
        if (O16) C16[(size_t)row * N + col] = f2bf(v);
      }
    }
  }
}

// ---------------- B/C skinny GEMMs (fp32) ----------------
__global__ __launch_bounds__(256) void bc_gemm(const float* __restrict__ xc,
    const float* __restrict__ WB, const float* __restrict__ WC,
    float* __restrict__ Bm, float* __restrict__ Cm)
{
  __shared__ float xs[8][DD];
  const int tid = threadIdx.x;
  const int l0 = blockIdx.x * 8;
  for (int idx = tid; idx < 8 * (DD / 4); idx += 256) {
    const int r = idx >> 8;
    const int c4 = (idx & 255) << 2;
    *(float4*)&xs[r][c4] = *(const float4*)&xc[(size_t)(l0 + r) * DD + c4];
  }
  __syncthreads();
  const int r = tid >> 5;
  const int col = tid & 31;
  const float* __restrict__ W = (col < 16) ? WB : WC;
  const int n = col & 15;
  float acc = 0.f;
  #pragma unroll 8
  for (int k = 0; k < DD; ++k) acc = fmaf(xs[r][k], W[k * NS + n], acc);
  if (col < 16) Bm[(l0 + r) * NS + n] = acc;
  else          Cm[(l0 + r) * NS + n] = acc;
}

// ---------------- selective scan (fp32, y emitted bf16) ----------------
__global__ __launch_bounds__(256) void ssm_scan(
    const float* __restrict__ delta, const float* __restrict__ xc,
    const float* __restrict__ Bmat, const float* __restrict__ Cmat,
    const float* __restrict__ A_log, unsigned short* __restrict__ y16)
{
  const int tid = threadIdx.x;
  const int n = tid & 15;
  const int dl = tid >> 4;
  const int d = blockIdx.x * 16 + dl;
  const float Av = -expf(A_log[d * NS + n]);
  float h = 0.f;
  float da[8], xa[8], ba[8], ca[8];
  float db[8], xb[8], bb[8], cb[8];

#define LOAD8(dv, xv, bv, cv, l0)                              \
  _Pragma("unroll")                                            \
  for (int u = 0; u < 8; ++u) {                                \
    dv[u] = delta[((l0) + u) * DD + d];                        \
    xv[u] = xc[((l0) + u) * DD + d];                           \
    bv[u] = Bmat[((l0) + u) * NS + n];                         \
    cv[u] = Cmat[((l0) + u) * NS + n];                         \
  }

#define STEP8(dv, xv, bv, cv, l0)                              \
  _Pragma("unroll")                                            \
  for (int u = 0; u < 8; ++u) {                                \
    const float abar = expf(dv[u] * Av);                       \
    h = fmaf(abar, h, dv[u] * xv[u] * bv[u]);                  \
    float contrib = h * cv[u];                                 \
    contrib += __shfl_xor(contrib, 1);                         \
    contrib += __shfl_xor(contrib, 2);                         \
    contrib += __shfl_xor(contrib, 4);                         \
    contrib += __shfl_xor(contrib, 8);                         \
    if (n == 0) y16[((l0) + u) * DD + d] = f2bf(contrib);      \
  }

  LOAD8(da, xa, ba, ca, 0);
  for (int l0 = 0; l0 < LL; l0 += 16) {
    LOAD8(db, xb, bb, cb, l0 + 8);
    STEP8(da, xa, ba, ca, l0);
    if (l0 + 16 < LL) { LOAD8(da, xa, ba, ca, l0 + 16); }
    STEP8(db, xb, bb, cb, l0 + 8);
  }
#undef LOAD8
#undef STEP8
}

// ---------------- launch ----------------
extern "C" void kernel_launch(void* const* d_in, const int* in_sizes, int n_in,
                              void* d_out, int out_size, void* d_ws, size_t ws_size,
                              hipStream_t stream) {
  const float* x       = (const float*)d_in[0];
  const float* W_proj  = (const float*)d_in[1];
  const float* b_proj  = (const float*)d_in[2];
  const float* conv_w  = (const float*)d_in[3];
  const float* conv_b  = (const float*)d_in[4];
  const float* A_log   = (const float*)d_in[5];
  const float* W_delta = (const float*)d_in[6];
  const float* W_B     = (const float*)d_in[7];
  const float* W_C     = (const float*)d_in[8];
  float* out = (float*)d_out;

  // Workspace layout (byte offsets). Peak ~28.3 MB; every region fully written
  // before read (0xAA poison harmless). Aliases noted.
  char* w = (char*)d_ws;
  const size_t MB = 1024 * 1024;
  unsigned short* x16     = (unsigned short*)(w + 0);        // 4 MB [2048][1024]
  float*          delta32 = (float*)(w + 0);                 // alias (after proj)
  unsigned short* wp16    = (unsigned short*)(w + 4 * MB);   // 2 MB
  unsigned short* cw16    = (unsigned short*)(w + 6 * MB);   // 6 MB [1024][3072]
  unsigned short* y16     = (unsigned short*)(w + 6 * MB);   // alias (after conv gemm)
  unsigned short* wdT16   = (unsigned short*)(w + 12 * MB);  // 2 MB [d][k]
  unsigned short* pbuf    = (unsigned short*)(w + 14 * MB);  // 4 MB: xm16 | xg16
  unsigned short* xm16    = pbuf;
  unsigned short* xg16    = pbuf + 1024 * 1024;
  unsigned short* xc16    = pbuf;                            // alias over xm (after xsht)
  unsigned short* xsht    = (unsigned short*)(w + 18 * MB);  // 6 MB [1024][3072]
  unsigned short* out116  = (unsigned short*)(w + 18 * MB);  // alias (after conv gemm)
  float*          xc32    = (float*)(w + 24 * MB);           // 4 MB
  float*          Bm      = (float*)(w + 28 * MB);           // 64 KB
  float*          Cm      = (float*)(w + 28 * MB + 65536);   // 64 KB

  const dim3 blk(256);

  // casts
  castk<<<dim3(2048), blk, 0, stream>>>(x, x16, 2 * 1024 * 1024);
  castk<<<dim3(1024), blk, 0, stream>>>(W_proj, wp16, 1024 * 1024);
  castk<<<dim3(3072), blk, 0, stream>>>(conv_w, cw16, 3 * 1024 * 1024);
  tcastk<<<dim3(16, 16), blk, 0, stream>>>(W_delta, wdT16);

  // p = x @ W_proj^T + b ; rows<1024 -> xm (no act), rows>=1024 -> xg (silu)
  gemm_bf16<64, 3, false, false, true><<<dim3(16, 16), blk, 0, stream>>>(
      x16, wp16, b_proj, nullptr, pbuf, 2048, 1024, 1024);
  // shifted-transposed conv activations
  build_xsht<<<dim3(16, 16), blk, 0, stream>>>(xm16, xsht);
  // xc = silu(conv(xm) + conv_b): implicit GEMM, K = 3072, row bias
  gemm_bf16<64, 1, true, true, true><<<dim3(16, 8), blk, 0, stream>>>(
      cw16, xsht, conv_b, xc32, xc16, 1024, 1024, 3072);
  // delta = softplus(xc @ W_delta)
  gemm_bf16<64, 2, false, true, false><<<dim3(16, 8), blk, 0, stream>>>(
      xc16, wdT16, nullptr, delta32, nullptr, 1024, 1024, 1024);
  // B, C
  bc_gemm<<<dim3(128), blk, 0, stream>>>(xc32, W_B, W_C, Bm, Cm);
  // selective scan -> y (bf16)
  ssm_scan<<<dim3(64), blk, 0, stream>>>(delta32, xc32, Bm, Cm, A_log, y16);
  // out1 = y @ xg^T
  gemm_bf16<64, 0, false, false, true><<<dim3(16, 8), blk, 0, stream>>>(
      y16, xg16, nullptr, nullptr, out116, 1024, 1024, 1024);
  // out = out1 @ W_proj^T + b
  gemm_bf16<64, 0, false, true, false><<<dim3(16, 8), blk, 0, stream>>>(
      out116, wp16, b_proj, out, nullptr, 1024, 1024, 1024);
}

// Round 4
// 331.789 us; speedup vs baseline: 2.7028x; 1.5796x over previous
//
#include <hip/hip_runtime.h>
#include <math.h>

// MambaBlock on MI355X: dense contractions via bf16 MFMA (16x16x32), fp32 acc.
// Selective scan: chunk-parallel 3-phase scan on transposed [d][l] operands.
// L == D == 1024, N == 16, K(conv) == 3.

#define LL 1024
#define DD 1024
#define NS 16
#define CCH 16      // scan chunks
#define CLEN 64     // 1024 / CCH

typedef short     bf16x8_t __attribute__((ext_vector_type(8)));
typedef float     f32x4_t  __attribute__((ext_vector_type(4)));
typedef unsigned short u16x4_t __attribute__((ext_vector_type(4)));
typedef unsigned short u16x8_t __attribute__((ext_vector_type(8)));

__device__ __forceinline__ float silu_f(float x) { return x / (1.f + expf(-x)); }
__device__ __forceinline__ float softplus_f(float x) {
  return fmaxf(x, 0.f) + log1pf(expf(-fabsf(x)));
}
__device__ __forceinline__ unsigned short f2bf(float f) {  // RNE
  unsigned int u = __float_as_uint(f);
  u += 0x7fffu + ((u >> 16) & 1u);
  return (unsigned short)(u >> 16);
}

// ---------------- small conversion kernels ----------------
__global__ __launch_bounds__(256) void castk(const float* __restrict__ in,
                                             unsigned short* __restrict__ out, int n) {
  int i = (blockIdx.x * 256 + threadIdx.x) * 4;
  if (i >= n) return;
  float4 v = *(const float4*)(in + i);
  u16x4_t o; o[0] = f2bf(v.x); o[1] = f2bf(v.y); o[2] = f2bf(v.z); o[3] = f2bf(v.w);
  *(u16x4_t*)(out + i) = o;
}

// out[d][k] = W[k][d]  (1024x1024), fp32 -> bf16
__global__ __launch_bounds__(256) void tcastk(const float* __restrict__ W,
                                              unsigned short* __restrict__ out) {
  __shared__ float T[64][65];
  const int t = threadIdx.x;
  const int r = t >> 2, cq = (t & 3) << 4;
  const int d0 = blockIdx.x * 64, k0 = blockIdx.y * 64;
  #pragma unroll
  for (int c = 0; c < 16; c += 4) {
    float4 v = *(const float4*)&W[(size_t)(k0 + r) * DD + d0 + cq + c];
    T[r][cq + c + 0] = v.x; T[r][cq + c + 1] = v.y;
    T[r][cq + c + 2] = v.z; T[r][cq + c + 3] = v.w;
  }
  __syncthreads();
  u16x8_t o0, o1;
  #pragma unroll
  for (int j = 0; j < 8; ++j) o0[j] = f2bf(T[cq + j][r]);
  #pragma unroll
  for (int j = 0; j < 8; ++j) o1[j] = f2bf(T[cq + 8 + j][r]);
  *(u16x8_t*)&out[(size_t)(d0 + r) * DD + k0 + cq] = o0;
  *(u16x8_t*)&out[(size_t)(d0 + r) * DD + k0 + cq + 8] = o1;
}

// fp32 transpose: out[c][r] = in[r][c], 1024x1024
__global__ __launch_bounds__(256) void transpose_f32(const float* __restrict__ in,
                                                     float* __restrict__ out) {
  __shared__ float T[64][65];
  const int t = threadIdx.x;
  const int r = t >> 4;          // 0..15
  const int cq = (t & 15) << 2;  // 0..60
  const int r0 = blockIdx.y * 64, c0 = blockIdx.x * 64;
  #pragma unroll
  for (int rr = 0; rr < 64; rr += 16) {
    float4 v = *(const float4*)&in[(size_t)(r0 + r + rr) * DD + c0 + cq];
    T[r + rr][cq + 0] = v.x; T[r + rr][cq + 1] = v.y;
    T[r + rr][cq + 2] = v.z; T[r + rr][cq + 3] = v.w;
  }
  __syncthreads();
  #pragma unroll
  for (int rr = 0; rr < 64; rr += 16) {
    float4 o;
    o.x = T[cq + 0][r + rr]; o.y = T[cq + 1][r + rr];
    o.z = T[cq + 2][r + rr]; o.w = T[cq + 3][r + rr];
    *(float4*)&out[(size_t)(c0 + r + rr) * LL + r0 + cq] = o;
  }
}

// XshT[w][i*3+k] = xm[i][w-1+k] (zero-padded), bf16 -> bf16. out is [1024][3072].
__global__ __launch_bounds__(256) void build_xsht(const unsigned short* __restrict__ xm,
                                                  unsigned short* __restrict__ out) {
  __shared__ unsigned short Xs[64][66];
  const int t = threadIdx.x;
  const int w0 = blockIdx.x * 64, i0 = blockIdx.y * 64;
  {
    const int r = t >> 2, cq = (t & 3) << 4;
    #pragma unroll
    for (int c = 0; c < 16; c += 4) {
      u16x4_t v = *(const u16x4_t*)&xm[(size_t)(i0 + r) * DD + w0 + cq + c];
      Xs[r][1 + cq + c + 0] = v[0]; Xs[r][1 + cq + c + 1] = v[1];
      Xs[r][1 + cq + c + 2] = v[2]; Xs[r][1 + cq + c + 3] = v[3];
    }
  }
  if (t < 64)                 Xs[t][0]       = (w0 > 0)        ? xm[(size_t)(i0 + t) * DD + w0 - 1]  : (unsigned short)0;
  else if (t < 128) { int r = t - 64; Xs[r][65] = (w0 + 64 < DD) ? xm[(size_t)(i0 + r) * DD + w0 + 64] : (unsigned short)0; }
  __syncthreads();
  const int wr = t >> 2, q = t & 3;
  unsigned short vals[48];
  #pragma unroll
  for (int ii = 0; ii < 16; ++ii)
    #pragma unroll
    for (int k = 0; k < 3; ++k)
      vals[ii * 3 + k] = Xs[q * 16 + ii][wr + k];
  #pragma unroll
  for (int s = 0; s < 6; ++s) {
    u16x8_t o;
    #pragma unroll
    for (int j = 0; j < 8; ++j) o[j] = vals[s * 8 + j];
    *(u16x8_t*)&out[(size_t)(w0 + wr) * 3072 + (size_t)i0 * 3 + q * 48 + s * 8] = o;
  }
}

// ---------------- bf16 MFMA GEMM: C = act(A[M,K] @ B[N,K]^T + bias) ----------------
// Tile 128 x NC, BK=32, 4 waves (2x2); wave = 64 x NC/2 (4 x NC/32 fragments).
// global_load_lds 16B staging, linear LDS dest, XOR chunk swizzle on source+read.
// ACT: 0 none, 1 silu, 2 softplus, 3 silu iff row>=1024. BROW: bias by row.
template<int NC, int ACT, bool BROW, bool O32, bool O16>
__global__ __launch_bounds__(256) void gemm_bf16(
    const unsigned short* __restrict__ A, const unsigned short* __restrict__ B,
    const float* __restrict__ bias, float* __restrict__ C32,
    unsigned short* __restrict__ C16, int M, int N, int K)
{
  constexpr int NFR = NC / 32;            // B fragments per wave
  constexpr int TCH = (128 + NC) * 4;     // 16B chunks per K-step (A then B)
  __shared__ unsigned short s[(128 + NC) * 32];
  const int tid  = threadIdx.x;
  const int lane = tid & 63;
  const int wv   = tid >> 6;
  const int wm   = wv >> 1, wn = wv & 1;
  const int m0 = blockIdx.y * 128, n0 = blockIdx.x * NC;
  const int wbase = tid & 192;  // wave-uniform

  f32x4_t acc[4][NFR];
  #pragma unroll
  for (int i = 0; i < 4; ++i)
    #pragma unroll
    for (int j = 0; j < NFR; ++j)
      acc[i][j] = (f32x4_t)(0.f);

  for (int k0 = 0; k0 < K; k0 += 32) {
    #pragma unroll
    for (int it = 0; it < TCH / 256; ++it) {
      const int c   = (it << 8) + tid;          // linear dest chunk id
      const bool isA = (c < 512);
      const int idx = isA ? c : c - 512;
      const int r   = idx >> 2;
      const int kcg = (idx & 3) ^ ((r >> 1) & 3);  // pre-swizzled source k-chunk
      const unsigned short* src = isA ? (A + (size_t)(m0 + r) * K + k0 + kcg * 8)
                                      : (B + (size_t)(n0 + r) * K + k0 + kcg * 8);
      __builtin_amdgcn_global_load_lds(
          (const __attribute__((address_space(1))) void*)src,
          (__attribute__((address_space(3))) void*)(s + (size_t)((it << 8) + wbase) * 8),
          16, 0, 0);
    }
    __syncthreads();

    const int rl = lane & 15, kc = lane >> 4;
    bf16x8_t af[4], bfr[NFR];
    #pragma unroll
    for (int mi = 0; mi < 4; ++mi) {
      const int row = wm * 64 + mi * 16 + rl;
      const int ch  = (row << 2) + (kc ^ ((row >> 1) & 3));
      af[mi] = *(const bf16x8_t*)(s + (size_t)ch * 8);
    }
    #pragma unroll
    for (int ni = 0; ni < NFR; ++ni) {
      const int col = wn * (NC / 2) + ni * 16 + rl;
      const int ch  = 512 + (col << 2) + (kc ^ ((col >> 1) & 3));
      bfr[ni] = *(const bf16x8_t*)(s + (size_t)ch * 8);
    }
    #pragma unroll
    for (int mi = 0; mi < 4; ++mi)
      #pragma unroll
      for (int ni = 0; ni < NFR; ++ni)
        acc[mi][ni] = __builtin_amdgcn_mfma_f32_16x16x32_bf16(af[mi], bfr[ni], acc[mi][ni], 0, 0, 0);
    __syncthreads();
  }

  const int rl = lane & 15, rg = lane >> 4;
  #pragma unroll
  for (int mi = 0; mi < 4; ++mi) {
    #pragma unroll
    for (int ni = 0; ni < NFR; ++ni) {
      const int col = n0 + wn * (NC / 2) + ni * 16 + rl;
      #pragma unroll
      for (int j = 0; j < 4; ++j) {
        const int row = m0 + wm * 64 + mi * 16 + rg * 4 + j;
        float v = acc[mi][ni][j];
        if (bias) v += BROW ? bias[row] : bias[col];
        if (ACT == 1) v = silu_f(v);
        else if (ACT == 2) v = softplus_f(v);
        else if (ACT == 3) { if (row >= 1024) v = silu_f(v); }
        if (O32) C32[(size_t)row * N + col] = v;
        if (O16) C16[(size_t)row * N + col] = f2bf(v);
      }
    }
  }
}

// ---------------- B/C skinny GEMMs (fp32) ----------------
__global__ __launch_bounds__(256) void bc_gemm(const float* __restrict__ xc,
    const float* __restrict__ WB, const float* __restrict__ WC,
    float* __restrict__ Bm, float* __restrict__ Cm)
{
  __shared__ float xs[8][DD];
  const int tid = threadIdx.x;
  const int l0 = blockIdx.x * 8;
  for (int idx = tid; idx < 8 * (DD / 4); idx += 256) {
    const int r = idx >> 8;
    const int c4 = (idx & 255) << 2;
    *(float4*)&xs[r][c4] = *(const float4*)&xc[(size_t)(l0 + r) * DD + c4];
  }
  __syncthreads();
  const int r = tid >> 5;
  const int col = tid & 31;
  const float* __restrict__ W = (col < 16) ? WB : WC;
  const int n = col & 15;
  float acc = 0.f;
  #pragma unroll 8
  for (int k = 0; k < DD; ++k) acc = fmaf(xs[r][k], W[k * NS + n], acc);
  if (col < 16) Bm[(l0 + r) * NS + n] = acc;
  else          Cm[(l0 + r) * NS + n] = acc;
}

// ---------------- chunk-parallel selective scan ----------------
// thread = (d, n); block = 16 d x 16 n; grid = (CCH, DD/16).
// Phase 1: per-chunk (prod Abar, local h end) with h_in = 0.
__global__ __launch_bounds__(256) void scan_p1(
    const float* __restrict__ deltaT, const float* __restrict__ xcT,
    const float* __restrict__ Bmat, const float* __restrict__ A_log,
    float* __restrict__ P, float* __restrict__ H)
{
  const int tid = threadIdx.x;
  const int n = tid & 15, dl = tid >> 4;
  const int d = blockIdx.y * 16 + dl;
  const int c = blockIdx.x;
  const int l0 = c * CLEN;
  const float Av = -expf(A_log[d * NS + n]);
  float h = 0.f, p = 1.f;
  for (int j = 0; j < CLEN; j += 4) {
    const float4 dv = *(const float4*)&deltaT[(size_t)d * LL + l0 + j];
    const float4 xv = *(const float4*)&xcT[(size_t)d * LL + l0 + j];
    const float dvu[4] = {dv.x, dv.y, dv.z, dv.w};
    const float xvu[4] = {xv.x, xv.y, xv.z, xv.w};
    #pragma unroll
    for (int u = 0; u < 4; ++u) {
      const float b = Bmat[(size_t)(l0 + j + u) * NS + n];
      const float ab = expf(dvu[u] * Av);
      h = fmaf(ab, h, dvu[u] * xvu[u] * b);
      p *= ab;
    }
  }
  const int idx = d * NS + n;
  P[(size_t)c * (DD * NS) + idx] = p;
  H[(size_t)c * (DD * NS) + idx] = h;
}

// Phase 2: carry combine across chunks: hin[c] = H[c-1] + P[c-1]*hin[c-1].
__global__ __launch_bounds__(256) void scan_p2(const float* __restrict__ P,
                                               const float* __restrict__ H,
                                               float* __restrict__ Hin) {
  const int idx = blockIdx.x * 256 + threadIdx.x;  // 0..16383
  float hin = 0.f;
  Hin[idx] = 0.f;
  #pragma unroll
  for (int c = 1; c < CCH; ++c) {
    hin = fmaf(P[(size_t)(c - 1) * (DD * NS) + idx], hin,
               H[(size_t)(c - 1) * (DD * NS) + idx]);
    Hin[(size_t)c * (DD * NS) + idx] = hin;
  }
}

// Phase 3: rescan from carry-in, emit y (bf16, [l][d]).
__global__ __launch_bounds__(256) void scan_p3(
    const float* __restrict__ deltaT, const float* __restrict__ xcT,
    const float* __restrict__ Bmat, const float* __restrict__ Cmat,
    const float* __restrict__ Hin, const float* __restrict__ A_log,
    unsigned short* __restrict__ y16)
{
  const int tid = threadIdx.x;
  const int n = tid & 15, dl = tid >> 4;
  const int d = blockIdx.y * 16 + dl;
  const int c = blockIdx.x;
  const int l0 = c * CLEN;
  const float Av = -expf(A_log[d * NS + n]);
  float h = Hin[(size_t)c * (DD * NS) + d * NS + n];
  for (int j = 0; j < CLEN; j += 4) {
    const float4 dv = *(const float4*)&deltaT[(size_t)d * LL + l0 + j];
    const float4 xv = *(const float4*)&xcT[(size_t)d * LL + l0 + j];
    const float dvu[4] = {dv.x, dv.y, dv.z, dv.w};
    const float xvu[4] = {xv.x, xv.y, xv.z, xv.w};
    #pragma unroll
    for (int u = 0; u < 4; ++u) {
      const int l = l0 + j + u;
      const float b = Bmat[(size_t)l * NS + n];
      const float ab = expf(dvu[u] * Av);
      h = fmaf(ab, h, dvu[u] * xvu[u] * b);
      float contrib = h * Cmat[(size_t)l * NS + n];
      contrib += __shfl_xor(contrib, 1);
      contrib += __shfl_xor(contrib, 2);
      contrib += __shfl_xor(contrib, 4);
      contrib += __shfl_xor(contrib, 8);
      if (n == 0) y16[(size_t)l * DD + d] = f2bf(contrib);
    }
  }
}

// ---------------- launch ----------------
extern "C" void kernel_launch(void* const* d_in, const int* in_sizes, int n_in,
                              void* d_out, int out_size, void* d_ws, size_t ws_size,
                              hipStream_t stream) {
  const float* x       = (const float*)d_in[0];
  const float* W_proj  = (const float*)d_in[1];
  const float* b_proj  = (const float*)d_in[2];
  const float* conv_w  = (const float*)d_in[3];
  const float* conv_b  = (const float*)d_in[4];
  const float* A_log   = (const float*)d_in[5];
  const float* W_delta = (const float*)d_in[6];
  const float* W_B     = (const float*)d_in[7];
  const float* W_C     = (const float*)d_in[8];
  float* out = (float*)d_out;

  // Workspace layout (byte offsets), peak 28 MB. Every region fully written
  // before read (0xAA poison harmless). Aliases (temporal) noted per step.
  char* w = (char*)d_ws;
  const size_t MB = 1024 * 1024;
  unsigned short* x16     = (unsigned short*)(w + 0);        // 4 MB   [2048][1024]
  float*          deltaT32= (float*)(w + 0);                 // alias: after proj gemm
  unsigned short* wp16    = (unsigned short*)(w + 4 * MB);   // 2 MB
  unsigned short* cw16    = (unsigned short*)(w + 6 * MB);   // 6 MB   [1024][3072]
  unsigned short* y16     = (unsigned short*)(w + 6 * MB);   // alias: after conv gemm
  float*          Pc      = (float*)(w + 8 * MB);            // 1 MB   [CCH][16384] (over cw16, dead)
  float*          Hc      = (float*)(w + 9 * MB);            // 1 MB
  float*          HinC    = (float*)(w + 10 * MB);           // 1 MB
  float*          Bm      = (float*)(w + 11 * MB);           // 64 KB  (over cw16, dead)
  float*          Cm      = (float*)(w + 11 * MB + 65536);   // 64 KB
  unsigned short* wdT16   = (unsigned short*)(w + 12 * MB);  // 2 MB   [d][k]
  unsigned short* pbuf    = (unsigned short*)(w + 14 * MB);  // 4 MB:  xm16 | xg16
  unsigned short* xm16    = pbuf;
  unsigned short* xg16    = pbuf + 1024 * 1024;
  unsigned short* xc16    = pbuf;                            // alias over xm (after xsht)
  unsigned short* xsht    = (unsigned short*)(w + 18 * MB);  // 6 MB   [1024][3072]
  unsigned short* out116  = (unsigned short*)(w + 18 * MB);  // alias: after conv gemm (2 MB)
  float*          xcT32   = (float*)(w + 20 * MB);           // 4 MB   (over xsht tail, dead)
  float*          xc32    = (float*)(w + 24 * MB);           // 4 MB
  (void)ws_size;

  const dim3 blk(256);

  // casts
  castk<<<dim3(2048), blk, 0, stream>>>(x, x16, 2 * 1024 * 1024);
  castk<<<dim3(1024), blk, 0, stream>>>(W_proj, wp16, 1024 * 1024);
  castk<<<dim3(3072), blk, 0, stream>>>(conv_w, cw16, 3 * 1024 * 1024);
  tcastk<<<dim3(16, 16), blk, 0, stream>>>(W_delta, wdT16);

  // p = x @ W_proj^T + b ; rows<1024 -> xm (no act), rows>=1024 -> xg (silu)
  gemm_bf16<64, 3, false, false, true><<<dim3(16, 16), blk, 0, stream>>>(
      x16, wp16, b_proj, nullptr, pbuf, 2048, 1024, 1024);
  // shifted-transposed conv activations
  build_xsht<<<dim3(16, 16), blk, 0, stream>>>(xm16, xsht);
  // xc = silu(conv(xm) + conv_b): implicit GEMM, K = 3072, row bias
  gemm_bf16<64, 1, true, true, true><<<dim3(16, 8), blk, 0, stream>>>(
      cw16, xsht, conv_b, xc32, xc16, 1024, 1024, 3072);
  // deltaT[d][l] = softplus(W_deltaT[d,:] . xc[l,:])  (swapped operands)
  gemm_bf16<64, 2, false, true, false><<<dim3(16, 8), blk, 0, stream>>>(
      wdT16, xc16, nullptr, deltaT32, nullptr, 1024, 1024, 1024);
  // xcT for the scan
  transpose_f32<<<dim3(16, 16), blk, 0, stream>>>(xc32, xcT32);
  // B, C
  bc_gemm<<<dim3(128), blk, 0, stream>>>(xc32, W_B, W_C, Bm, Cm);
  // chunk-parallel scan
  scan_p1<<<dim3(CCH, DD / 16), blk, 0, stream>>>(deltaT32, xcT32, Bm, A_log, Pc, Hc);
  scan_p2<<<dim3(64), blk, 0, stream>>>(Pc, Hc, HinC);
  scan_p3<<<dim3(CCH, DD / 16), blk, 0, stream>>>(deltaT32, xcT32, Bm, Cm, HinC, A_log, y16);
  // out1 = y @ xg^T
  gemm_bf16<64, 0, false, false, true><<<dim3(16, 8), blk, 0, stream>>>(
      y16, xg16, nullptr, nullptr, out116, 1024, 1024, 1024);
  // out = out1 @ W_proj^T + b
  gemm_bf16<64, 0, false, true, false><<<dim3(16, 8), blk, 0, stream>>>(
      out116, wp16, b_proj, out, nullptr, 1024, 1024, 1024);
}

// Round 5
// 262.291 us; speedup vs baseline: 3.4189x; 1.2650x over previous
//
#include <hip/hip_runtime.h>
#include <math.h>

// MambaBlock on MI355X: dense contractions via bf16 MFMA (16x16x32), fp32 acc.
// GEMM: double-buffered LDS, BK=64, stage-next-before-compute (T3 minimal),
// one barrier per K-step. Tiles sized so every GEMM has 256 blocks.
// Selective scan: chunk-parallel 3-phase scan on transposed [d][l] operands.

#define LL 1024
#define DD 1024
#define NS 16
#define CCH 16      // scan chunks
#define CLEN 64     // 1024 / CCH

typedef short     bf16x8_t __attribute__((ext_vector_type(8)));
typedef float     f32x4_t  __attribute__((ext_vector_type(4)));
typedef unsigned short u16x4_t __attribute__((ext_vector_type(4)));
typedef unsigned short u16x8_t __attribute__((ext_vector_type(8)));

__device__ __forceinline__ float silu_f(float x) { return x / (1.f + expf(-x)); }
__device__ __forceinline__ float softplus_f(float x) {
  return fmaxf(x, 0.f) + log1pf(expf(-fabsf(x)));
}
__device__ __forceinline__ unsigned short f2bf(float f) {  // RNE
  unsigned int u = __float_as_uint(f);
  u += 0x7fffu + ((u >> 16) & 1u);
  return (unsigned short)(u >> 16);
}

// ---------------- small conversion kernels ----------------
__global__ __launch_bounds__(256) void castk(const float* __restrict__ in,
                                             unsigned short* __restrict__ out, int n) {
  int i = (blockIdx.x * 256 + threadIdx.x) * 4;
  if (i >= n) return;
  float4 v = *(const float4*)(in + i);
  u16x4_t o; o[0] = f2bf(v.x); o[1] = f2bf(v.y); o[2] = f2bf(v.z); o[3] = f2bf(v.w);
  *(u16x4_t*)(out + i) = o;
}

// out[d][k] = W[k][d]  (1024x1024), fp32 -> bf16
__global__ __launch_bounds__(256) void tcastk(const float* __restrict__ W,
                                              unsigned short* __restrict__ out) {
  __shared__ float T[64][65];
  const int t = threadIdx.x;
  const int r = t >> 2, cq = (t & 3) << 4;
  const int d0 = blockIdx.x * 64, k0 = blockIdx.y * 64;
  #pragma unroll
  for (int c = 0; c < 16; c += 4) {
    float4 v = *(const float4*)&W[(size_t)(k0 + r) * DD + d0 + cq + c];
    T[r][cq + c + 0] = v.x; T[r][cq + c + 1] = v.y;
    T[r][cq + c + 2] = v.z; T[r][cq + c + 3] = v.w;
  }
  __syncthreads();
  u16x8_t o0, o1;
  #pragma unroll
  for (int j = 0; j < 8; ++j) o0[j] = f2bf(T[cq + j][r]);
  #pragma unroll
  for (int j = 0; j < 8; ++j) o1[j] = f2bf(T[cq + 8 + j][r]);
  *(u16x8_t*)&out[(size_t)(d0 + r) * DD + k0 + cq] = o0;
  *(u16x8_t*)&out[(size_t)(d0 + r) * DD + k0 + cq + 8] = o1;
}

// fp32 transpose: out[c][r] = in[r][c], 1024x1024
__global__ __launch_bounds__(256) void transpose_f32(const float* __restrict__ in,
                                                     float* __restrict__ out) {
  __shared__ float T[64][65];
  const int t = threadIdx.x;
  const int r = t >> 4;          // 0..15
  const int cq = (t & 15) << 2;  // 0..60
  const int r0 = blockIdx.y * 64, c0 = blockIdx.x * 64;
  #pragma unroll
  for (int rr = 0; rr < 64; rr += 16) {
    float4 v = *(const float4*)&in[(size_t)(r0 + r + rr) * DD + c0 + cq];
    T[r + rr][cq + 0] = v.x; T[r + rr][cq + 1] = v.y;
    T[r + rr][cq + 2] = v.z; T[r + rr][cq + 3] = v.w;
  }
  __syncthreads();
  #pragma unroll
  for (int rr = 0; rr < 64; rr += 16) {
    float4 o;
    o.x = T[cq + 0][r + rr]; o.y = T[cq + 1][r + rr];
    o.z = T[cq + 2][r + rr]; o.w = T[cq + 3][r + rr];
    *(float4*)&out[(size_t)(c0 + r + rr) * LL + r0 + cq] = o;
  }
}

// XshT[w][i*3+k] = xm[i][w-1+k] (zero-padded), bf16 -> bf16. out is [1024][3072].
__global__ __launch_bounds__(256) void build_xsht(const unsigned short* __restrict__ xm,
                                                  unsigned short* __restrict__ out) {
  __shared__ unsigned short Xs[64][66];
  const int t = threadIdx.x;
  const int w0 = blockIdx.x * 64, i0 = blockIdx.y * 64;
  {
    const int r = t >> 2, cq = (t & 3) << 4;
    #pragma unroll
    for (int c = 0; c < 16; c += 4) {
      u16x4_t v = *(const u16x4_t*)&xm[(size_t)(i0 + r) * DD + w0 + cq + c];
      Xs[r][1 + cq + c + 0] = v[0]; Xs[r][1 + cq + c + 1] = v[1];
      Xs[r][1 + cq + c + 2] = v[2]; Xs[r][1 + cq + c + 3] = v[3];
    }
  }
  if (t < 64)                 Xs[t][0]       = (w0 > 0)        ? xm[(size_t)(i0 + t) * DD + w0 - 1]  : (unsigned short)0;
  else if (t < 128) { int r = t - 64; Xs[r][65] = (w0 + 64 < DD) ? xm[(size_t)(i0 + r) * DD + w0 + 64] : (unsigned short)0; }
  __syncthreads();
  const int wr = t >> 2, q = t & 3;
  unsigned short vals[48];
  #pragma unroll
  for (int ii = 0; ii < 16; ++ii)
    #pragma unroll
    for (int k = 0; k < 3; ++k)
      vals[ii * 3 + k] = Xs[q * 16 + ii][wr + k];
  #pragma unroll
  for (int s = 0; s < 6; ++s) {
    u16x8_t o;
    #pragma unroll
    for (int j = 0; j < 8; ++j) o[j] = vals[s * 8 + j];
    *(u16x8_t*)&out[(size_t)(w0 + wr) * 3072 + (size_t)i0 * 3 + q * 48 + s * 8] = o;
  }
}

// ------------- bf16 MFMA GEMM: C = act(A[M,K] @ B[N,K]^T + bias) -------------
// Tile TM x NC, BK=64, 4 waves (2x2). Double-buffered LDS; per K-step:
// {issue next-tile global_load_lds -> ds_read+MFMA current -> barrier}.
// Linear LDS dest, chunk^=(row&7) swizzle on source+read (involution).
// ACT: 0 none, 1 silu, 2 softplus, 3 silu iff row>=1024. BROW: bias by row.
template<int TM, int NC, int ACT, bool BROW, bool O32, bool O16>
__global__ __launch_bounds__(256) void gemm_bf16(
    const unsigned short* __restrict__ A, const unsigned short* __restrict__ B,
    const float* __restrict__ bias, float* __restrict__ C32,
    unsigned short* __restrict__ C16, int M, int N, int K)
{
  constexpr int MI   = TM / 32;          // A fragments per wave
  constexpr int NI   = NC / 32;          // B fragments per wave
  constexpr int ROWS = TM + NC;
  constexpr int GI   = ROWS * 8 / 256;   // glds per thread per stage
  __shared__ unsigned short s[2][ROWS * 64];
  const int tid  = threadIdx.x;
  const int lane = tid & 63;
  const int wv   = tid >> 6;
  const int wm   = wv >> 1, wn = wv & 1;
  const int m0 = blockIdx.y * TM, n0 = blockIdx.x * NC;
  const int wbase = tid & 192;  // wave-uniform

  f32x4_t acc[MI][NI];
  #pragma unroll
  for (int i = 0; i < MI; ++i)
    #pragma unroll
    for (int j = 0; j < NI; ++j)
      acc[i][j] = (f32x4_t)(0.f);

  auto stage = [&](int buf, int k0) {
    #pragma unroll
    for (int it = 0; it < GI; ++it) {
      const int c   = (it << 8) + tid;        // linear dest chunk id
      const int r   = c >> 3;                 // LDS row (A rows then B rows)
      const int kcg = (c & 7) ^ (r & 7);      // pre-swizzled source k-chunk
      const unsigned short* src = (r < TM)
          ? (A + (size_t)(m0 + r) * K + k0 + kcg * 8)
          : (B + (size_t)(n0 + r - TM) * K + k0 + kcg * 8);
      __builtin_amdgcn_global_load_lds(
          (const __attribute__((address_space(1))) void*)src,
          (__attribute__((address_space(3))) void*)(&s[buf][0] + (size_t)((it << 8) + wbase) * 8),
          16, 0, 0);
    }
  };

  stage(0, 0);
  __syncthreads();

  const int NT = K >> 6;
  int cur = 0;
  for (int t = 0; t < NT; ++t) {
    if (t + 1 < NT) stage(cur ^ 1, (t + 1) << 6);

    const int rl = lane & 15, kq = lane >> 4;
    bf16x8_t af[MI][2], bfr[NI][2];
    #pragma unroll
    for (int mi = 0; mi < MI; ++mi) {
      const int row = wm * (TM / 2) + mi * 16 + rl;
      #pragma unroll
      for (int ks = 0; ks < 2; ++ks) {
        const int ch = row * 8 + ((ks * 4 + kq) ^ (row & 7));
        af[mi][ks] = *(const bf16x8_t*)(&s[cur][0] + (size_t)ch * 8);
      }
    }
    #pragma unroll
    for (int ni = 0; ni < NI; ++ni) {
      const int row = TM + wn * (NC / 2) + ni * 16 + rl;
      #pragma unroll
      for (int ks = 0; ks < 2; ++ks) {
        const int ch = row * 8 + ((ks * 4 + kq) ^ (row & 7));
        bfr[ni][ks] = *(const bf16x8_t*)(&s[cur][0] + (size_t)ch * 8);
      }
    }
    #pragma unroll
    for (int mi = 0; mi < MI; ++mi)
      #pragma unroll
      for (int ni = 0; ni < NI; ++ni)
        #pragma unroll
        for (int ks = 0; ks < 2; ++ks)
          acc[mi][ni] = __builtin_amdgcn_mfma_f32_16x16x32_bf16(
              af[mi][ks], bfr[ni][ks], acc[mi][ni], 0, 0, 0);
    __syncthreads();
    cur ^= 1;
  }

  const int rl = lane & 15, rg = lane >> 4;
  #pragma unroll
  for (int mi = 0; mi < MI; ++mi) {
    #pragma unroll
    for (int ni = 0; ni < NI; ++ni) {
      const int col = n0 + wn * (NC / 2) + ni * 16 + rl;
      #pragma unroll
      for (int j = 0; j < 4; ++j) {
        const int row = m0 + wm * (TM / 2) + mi * 16 + rg * 4 + j;
        float v = acc[mi][ni][j];
        if (bias) v += BROW ? bias[row] : bias[col];
        if (ACT == 1) v = silu_f(v);
        else if (ACT == 2) v = softplus_f(v);
        else if (ACT == 3) { if (row >= 1024) v = silu_f(v); }
        if (O32) C32[(size_t)row * N + col] = v;
        if (O16) C16[(size_t)row * N + col] = f2bf(v);
      }
    }
  }
}

// ---------------- B/C skinny GEMMs (fp32) ----------------
__global__ __launch_bounds__(256) void bc_gemm(const float* __restrict__ xc,
    const float* __restrict__ WB, const float* __restrict__ WC,
    float* __restrict__ Bm, float* __restrict__ Cm)
{
  __shared__ float xs[8][DD];
  const int tid = threadIdx.x;
  const int l0 = blockIdx.x * 8;
  for (int idx = tid; idx < 8 * (DD / 4); idx += 256) {
    const int r = idx >> 8;
    const int c4 = (idx & 255) << 2;
    *(float4*)&xs[r][c4] = *(const float4*)&xc[(size_t)(l0 + r) * DD + c4];
  }
  __syncthreads();
  const int r = tid >> 5;
  const int col = tid & 31;
  const float* __restrict__ W = (col < 16) ? WB : WC;
  const int n = col & 15;
  float acc = 0.f;
  #pragma unroll 8
  for (int k = 0; k < DD; ++k) acc = fmaf(xs[r][k], W[k * NS + n], acc);
  if (col < 16) Bm[(l0 + r) * NS + n] = acc;
  else          Cm[(l0 + r) * NS + n] = acc;
}

// ---------------- chunk-parallel selective scan ----------------
__global__ __launch_bounds__(256) void scan_p1(
    const float* __restrict__ deltaT, const float* __restrict__ xcT,
    const float* __restrict__ Bmat, const float* __restrict__ A_log,
    float* __restrict__ P, float* __restrict__ H)
{
  const int tid = threadIdx.x;
  const int n = tid & 15, dl = tid >> 4;
  const int d = blockIdx.y * 16 + dl;
  const int c = blockIdx.x;
  const int l0 = c * CLEN;
  const float Av = -expf(A_log[d * NS + n]);
  float h = 0.f, p = 1.f;
  for (int j = 0; j < CLEN; j += 4) {
    const float4 dv = *(const float4*)&deltaT[(size_t)d * LL + l0 + j];
    const float4 xv = *(const float4*)&xcT[(size_t)d * LL + l0 + j];
    const float dvu[4] = {dv.x, dv.y, dv.z, dv.w};
    const float xvu[4] = {xv.x, xv.y, xv.z, xv.w};
    #pragma unroll
    for (int u = 0; u < 4; ++u) {
      const float b = Bmat[(size_t)(l0 + j + u) * NS + n];
      const float ab = expf(dvu[u] * Av);
      h = fmaf(ab, h, dvu[u] * xvu[u] * b);
      p *= ab;
    }
  }
  const int idx = d * NS + n;
  P[(size_t)c * (DD * NS) + idx] = p;
  H[(size_t)c * (DD * NS) + idx] = h;
}

__global__ __launch_bounds__(256) void scan_p2(const float* __restrict__ P,
                                               const float* __restrict__ H,
                                               float* __restrict__ Hin) {
  const int idx = blockIdx.x * 256 + threadIdx.x;  // 0..16383
  float hin = 0.f;
  Hin[idx] = 0.f;
  #pragma unroll
  for (int c = 1; c < CCH; ++c) {
    hin = fmaf(P[(size_t)(c - 1) * (DD * NS) + idx], hin,
               H[(size_t)(c - 1) * (DD * NS) + idx]);
    Hin[(size_t)c * (DD * NS) + idx] = hin;
  }
}

__global__ __launch_bounds__(256) void scan_p3(
    const float* __restrict__ deltaT, const float* __restrict__ xcT,
    const float* __restrict__ Bmat, const float* __restrict__ Cmat,
    const float* __restrict__ Hin, const float* __restrict__ A_log,
    unsigned short* __restrict__ y16)
{
  const int tid = threadIdx.x;
  const int n = tid & 15, dl = tid >> 4;
  const int d = blockIdx.y * 16 + dl;
  const int c = blockIdx.x;
  const int l0 = c * CLEN;
  const float Av = -expf(A_log[d * NS + n]);
  float h = Hin[(size_t)c * (DD * NS) + d * NS + n];
  for (int j = 0; j < CLEN; j += 4) {
    const float4 dv = *(const float4*)&deltaT[(size_t)d * LL + l0 + j];
    const float4 xv = *(const float4*)&xcT[(size_t)d * LL + l0 + j];
    const float dvu[4] = {dv.x, dv.y, dv.z, dv.w};
    const float xvu[4] = {xv.x, xv.y, xv.z, xv.w};
    #pragma unroll
    for (int u = 0; u < 4; ++u) {
      const int l = l0 + j + u;
      const float b = Bmat[(size_t)l * NS + n];
      const float ab = expf(dvu[u] * Av);
      h = fmaf(ab, h, dvu[u] * xvu[u] * b);
      float contrib = h * Cmat[(size_t)l * NS + n];
      contrib += __shfl_xor(contrib, 1);
      contrib += __shfl_xor(contrib, 2);
      contrib += __shfl_xor(contrib, 4);
      contrib += __shfl_xor(contrib, 8);
      if (n == 0) y16[(size_t)l * DD + d] = f2bf(contrib);
    }
  }
}

// ---------------- launch ----------------
extern "C" void kernel_launch(void* const* d_in, const int* in_sizes, int n_in,
                              void* d_out, int out_size, void* d_ws, size_t ws_size,
                              hipStream_t stream) {
  const float* x       = (const float*)d_in[0];
  const float* W_proj  = (const float*)d_in[1];
  const float* b_proj  = (const float*)d_in[2];
  const float* conv_w  = (const float*)d_in[3];
  const float* conv_b  = (const float*)d_in[4];
  const float* A_log   = (const float*)d_in[5];
  const float* W_delta = (const float*)d_in[6];
  const float* W_B     = (const float*)d_in[7];
  const float* W_C     = (const float*)d_in[8];
  float* out = (float*)d_out;

  // Workspace layout (byte offsets), peak 28 MB. Every region fully written
  // before read (0xAA poison harmless). Aliases (temporal) noted per step.
  char* w = (char*)d_ws;
  const size_t MB = 1024 * 1024;
  unsigned short* x16     = (unsigned short*)(w + 0);        // 4 MB   [2048][1024]
  float*          deltaT32= (float*)(w + 0);                 // alias: after proj gemm
  unsigned short* wp16    = (unsigned short*)(w + 4 * MB);   // 2 MB
  unsigned short* cw16    = (unsigned short*)(w + 6 * MB);   // 6 MB   [1024][3072]
  unsigned short* y16     = (unsigned short*)(w + 6 * MB);   // alias: after conv gemm
  float*          Pc      = (float*)(w + 8 * MB);            // 1 MB   [CCH][16384] (over cw16, dead)
  float*          Hc      = (float*)(w + 9 * MB);            // 1 MB
  float*          HinC    = (float*)(w + 10 * MB);           // 1 MB
  float*          Bm      = (float*)(w + 11 * MB);           // 64 KB  (over cw16, dead)
  float*          Cm      = (float*)(w + 11 * MB + 65536);   // 64 KB
  unsigned short* wdT16   = (unsigned short*)(w + 12 * MB);  // 2 MB   [d][k]
  unsigned short* pbuf    = (unsigned short*)(w + 14 * MB);  // 4 MB:  xm16 | xg16
  unsigned short* xm16    = pbuf;
  unsigned short* xg16    = pbuf + 1024 * 1024;
  unsigned short* xc16    = pbuf;                            // alias over xm (after xsht)
  unsigned short* xsht    = (unsigned short*)(w + 18 * MB);  // 6 MB   [1024][3072]
  unsigned short* out116  = (unsigned short*)(w + 18 * MB);  // alias: after conv gemm (2 MB)
  float*          xcT32   = (float*)(w + 20 * MB);           // 4 MB   (over xsht tail, dead)
  float*          xc32    = (float*)(w + 24 * MB);           // 4 MB
  (void)ws_size;

  const dim3 blk(256);

  // casts
  castk<<<dim3(2048), blk, 0, stream>>>(x, x16, 2 * 1024 * 1024);
  castk<<<dim3(1024), blk, 0, stream>>>(W_proj, wp16, 1024 * 1024);
  castk<<<dim3(3072), blk, 0, stream>>>(conv_w, cw16, 3 * 1024 * 1024);
  tcastk<<<dim3(16, 16), blk, 0, stream>>>(W_delta, wdT16);

  // p = x @ W_proj^T + b ; rows<1024 -> xm (no act), rows>=1024 -> xg (silu)
  gemm_bf16<128, 64, 3, false, false, true><<<dim3(16, 16), blk, 0, stream>>>(
      x16, wp16, b_proj, nullptr, pbuf, 2048, 1024, 1024);
  // shifted-transposed conv activations
  build_xsht<<<dim3(16, 16), blk, 0, stream>>>(xm16, xsht);
  // xc = silu(conv(xm) + conv_b): implicit GEMM, K = 3072, row bias
  gemm_bf16<64, 64, 1, true, true, true><<<dim3(16, 16), blk, 0, stream>>>(
      cw16, xsht, conv_b, xc32, xc16, 1024, 1024, 3072);
  // deltaT[d][l] = softplus(W_deltaT[d,:] . xc[l,:])  (swapped operands)
  gemm_bf16<64, 64, 2, false, true, false><<<dim3(16, 16), blk, 0, stream>>>(
      wdT16, xc16, nullptr, deltaT32, nullptr, 1024, 1024, 1024);
  // xcT for the scan
  transpose_f32<<<dim3(16, 16), blk, 0, stream>>>(xc32, xcT32);
  // B, C
  bc_gemm<<<dim3(128), blk, 0, stream>>>(xc32, W_B, W_C, Bm, Cm);
  // chunk-parallel scan
  scan_p1<<<dim3(CCH, DD / 16), blk, 0, stream>>>(deltaT32, xcT32, Bm, A_log, Pc, Hc);
  scan_p2<<<dim3(64), blk, 0, stream>>>(Pc, Hc, HinC);
  scan_p3<<<dim3(CCH, DD / 16), blk, 0, stream>>>(deltaT32, xcT32, Bm, Cm, HinC, A_log, y16);
  // out1 = y @ xg^T
  gemm_bf16<64, 64, 0, false, false, true><<<dim3(16, 16), blk, 0, stream>>>(
      y16, xg16, nullptr, nullptr, out116, 1024, 1024, 1024);
  // out = out1 @ W_proj^T + b
  gemm_bf16<64, 64, 0, false, true, false><<<dim3(16, 16), blk, 0, stream>>>(
      out116, wp16, b_proj, out, nullptr, 1024, 1024, 1024);
}

// Round 6
// 204.591 us; speedup vs baseline: 4.3831x; 1.2820x over previous
//
#include <hip/hip_runtime.h>
#include <math.h>

// MambaBlock on MI355X: dense contractions via bf16 MFMA (16x16x32), fp32 acc.
// GEMM: 3-buffer LDS pipeline, counted s_waitcnt vmcnt(N) + raw s_barrier
// (T3/T4 minimal: one stage always in flight across the barrier).
// B/C projections folded into the delta GEMM (combined M=1088).
// Selective scan: chunk-parallel 3-phase scan on [d][l] / [n][l] operands.

#define LL 1024
#define DD 1024
#define NS 16
#define CCH 16      // scan chunks
#define CLEN 64     // 1024 / CCH

typedef short     bf16x8_t __attribute__((ext_vector_type(8)));
typedef float     f32x4_t  __attribute__((ext_vector_type(4)));
typedef unsigned short u16x4_t __attribute__((ext_vector_type(4)));
typedef unsigned short u16x8_t __attribute__((ext_vector_type(8)));

__device__ __forceinline__ float silu_f(float x) { return x / (1.f + expf(-x)); }
__device__ __forceinline__ float softplus_f(float x) {
  return fmaxf(x, 0.f) + log1pf(expf(-fabsf(x)));
}
__device__ __forceinline__ unsigned short f2bf(float f) {  // RNE
  unsigned int u = __float_as_uint(f);
  u += 0x7fffu + ((u >> 16) & 1u);
  return (unsigned short)(u >> 16);
}

template<int N> __device__ __forceinline__ void s_wait_vmcnt() {
  asm volatile("s_waitcnt vmcnt(%0)" :: "n"(N) : "memory");
}
__device__ __forceinline__ void raw_barrier() {
  asm volatile("s_barrier" ::: "memory");
}

// ---------------- small conversion kernels ----------------
__global__ __launch_bounds__(256) void castk(const float* __restrict__ in,
                                             unsigned short* __restrict__ out, int n) {
  int i = (blockIdx.x * 256 + threadIdx.x) * 4;
  if (i >= n) return;
  float4 v = *(const float4*)(in + i);
  u16x4_t o; o[0] = f2bf(v.x); o[1] = f2bf(v.y); o[2] = f2bf(v.z); o[3] = f2bf(v.w);
  *(u16x4_t*)(out + i) = o;
}

// out[d][k] = W[k][d]  (1024x1024), fp32 -> bf16
__global__ __launch_bounds__(256) void tcastk(const float* __restrict__ W,
                                              unsigned short* __restrict__ out) {
  __shared__ float T[64][65];
  const int t = threadIdx.x;
  const int r = t >> 2, cq = (t & 3) << 4;
  const int d0 = blockIdx.x * 64, k0 = blockIdx.y * 64;
  #pragma unroll
  for (int c = 0; c < 16; c += 4) {
    float4 v = *(const float4*)&W[(size_t)(k0 + r) * DD + d0 + cq + c];
    T[r][cq + c + 0] = v.x; T[r][cq + c + 1] = v.y;
    T[r][cq + c + 2] = v.z; T[r][cq + c + 3] = v.w;
  }
  __syncthreads();
  u16x8_t o0, o1;
  #pragma unroll
  for (int j = 0; j < 8; ++j) o0[j] = f2bf(T[cq + j][r]);
  #pragma unroll
  for (int j = 0; j < 8; ++j) o1[j] = f2bf(T[cq + 8 + j][r]);
  *(u16x8_t*)&out[(size_t)(d0 + r) * DD + k0 + cq] = o0;
  *(u16x8_t*)&out[(size_t)(d0 + r) * DD + k0 + cq + 8] = o1;
}

// Rows 1024..1087 of wcomb: [W_B^T (16); W_C^T (16); zeros (32)], bf16.
// grid 64 blocks; block b -> combined row 1024+b; thread t -> cols 4t..4t+3.
__global__ __launch_bounds__(256) void bct_cast(const float* __restrict__ WB,
                                                const float* __restrict__ WC,
                                                unsigned short* __restrict__ wcomb) {
  const int b = blockIdx.x;         // 0..63
  const int k = threadIdx.x * 4;    // 0..1020
  u16x4_t o;
  if (b < 32) {
    const float* W = (b < 16) ? WB : WC;
    const int n = b & 15;
    #pragma unroll
    for (int j = 0; j < 4; ++j) o[j] = f2bf(W[(size_t)(k + j) * NS + n]);
  } else {
    o[0] = o[1] = o[2] = o[3] = 0;
  }
  *(u16x4_t*)&wcomb[(size_t)(1024 + b) * DD + k] = o;
}

// fp32 transpose: out[c][r] = in[r][c], 1024x1024
__global__ __launch_bounds__(256) void transpose_f32(const float* __restrict__ in,
                                                     float* __restrict__ out) {
  __shared__ float T[64][65];
  const int t = threadIdx.x;
  const int r = t >> 4;          // 0..15
  const int cq = (t & 15) << 2;  // 0..60
  const int r0 = blockIdx.y * 64, c0 = blockIdx.x * 64;
  #pragma unroll
  for (int rr = 0; rr < 64; rr += 16) {
    float4 v = *(const float4*)&in[(size_t)(r0 + r + rr) * DD + c0 + cq];
    T[r + rr][cq + 0] = v.x; T[r + rr][cq + 1] = v.y;
    T[r + rr][cq + 2] = v.z; T[r + rr][cq + 3] = v.w;
  }
  __syncthreads();
  #pragma unroll
  for (int rr = 0; rr < 64; rr += 16) {
    float4 o;
    o.x = T[cq + 0][r + rr]; o.y = T[cq + 1][r + rr];
    o.z = T[cq + 2][r + rr]; o.w = T[cq + 3][r + rr];
    *(float4*)&out[(size_t)(c0 + r + rr) * LL + r0 + cq] = o;
  }
}

// XshT[w][i*3+k] = xm[i][w-1+k] (zero-padded), bf16 -> bf16. out is [1024][3072].
__global__ __launch_bounds__(256) void build_xsht(const unsigned short* __restrict__ xm,
                                                  unsigned short* __restrict__ out) {
  __shared__ unsigned short Xs[64][66];
  const int t = threadIdx.x;
  const int w0 = blockIdx.x * 64, i0 = blockIdx.y * 64;
  {
    const int r = t >> 2, cq = (t & 3) << 4;
    #pragma unroll
    for (int c = 0; c < 16; c += 4) {
      u16x4_t v = *(const u16x4_t*)&xm[(size_t)(i0 + r) * DD + w0 + cq + c];
      Xs[r][1 + cq + c + 0] = v[0]; Xs[r][1 + cq + c + 1] = v[1];
      Xs[r][1 + cq + c + 2] = v[2]; Xs[r][1 + cq + c + 3] = v[3];
    }
  }
  if (t < 64)                 Xs[t][0]       = (w0 > 0)        ? xm[(size_t)(i0 + t) * DD + w0 - 1]  : (unsigned short)0;
  else if (t < 128) { int r = t - 64; Xs[r][65] = (w0 + 64 < DD) ? xm[(size_t)(i0 + r) * DD + w0 + 64] : (unsigned short)0; }
  __syncthreads();
  const int wr = t >> 2, q = t & 3;
  unsigned short vals[48];
  #pragma unroll
  for (int ii = 0; ii < 16; ++ii)
    #pragma unroll
    for (int k = 0; k < 3; ++k)
      vals[ii * 3 + k] = Xs[q * 16 + ii][wr + k];
  #pragma unroll
  for (int s = 0; s < 6; ++s) {
    u16x8_t o;
    #pragma unroll
    for (int j = 0; j < 8; ++j) o[j] = vals[s * 8 + j];
    *(u16x8_t*)&out[(size_t)(w0 + wr) * 3072 + (size_t)i0 * 3 + q * 48 + s * 8] = o;
  }
}

// ------------- bf16 MFMA GEMM: C = act(A[M,K] @ B[N,K]^T + bias) -------------
// Tile TM x NC, BK=64, 4 waves (2x2). 3-buffer LDS pipeline: stage t+2 before
// compute t; counted s_waitcnt vmcnt(GI) + raw s_barrier keeps one stage in
// flight across the barrier. Linear LDS dest, chunk^=(row&7) swizzle on
// source+read (involution).
// ACT: 0 none, 1 silu, 2 softplus, 3 silu iff row>=1024, 4 softplus iff row<1024.
template<int TM, int NC, int ACT, bool BROW, bool O32, bool O16>
__global__ __launch_bounds__(256) void gemm_bf16(
    const unsigned short* __restrict__ A, const unsigned short* __restrict__ B,
    const float* __restrict__ bias, float* __restrict__ C32,
    unsigned short* __restrict__ C16, int M, int N, int K)
{
  constexpr int MI   = TM / 32;          // A fragments per wave
  constexpr int NI   = NC / 32;          // B fragments per wave
  constexpr int ROWS = TM + NC;
  constexpr int GI   = ROWS * 8 / 256;   // glds per thread per stage
  __shared__ unsigned short s[3][ROWS * 64];
  const int tid  = threadIdx.x;
  const int lane = tid & 63;
  const int wv   = tid >> 6;
  const int wm   = wv >> 1, wn = wv & 1;
  const int m0 = blockIdx.y * TM, n0 = blockIdx.x * NC;
  const int wbase = tid & 192;  // wave-uniform

  f32x4_t acc[MI][NI];
  #pragma unroll
  for (int i = 0; i < MI; ++i)
    #pragma unroll
    for (int j = 0; j < NI; ++j)
      acc[i][j] = (f32x4_t)(0.f);

  auto stage = [&](int buf, int k0) {
    #pragma unroll
    for (int it = 0; it < GI; ++it) {
      const int c   = (it << 8) + tid;        // linear dest chunk id
      const int r   = c >> 3;                 // LDS row (A rows then B rows)
      const int kcg = (c & 7) ^ (r & 7);      // pre-swizzled source k-chunk
      const unsigned short* src = (r < TM)
          ? (A + (size_t)(m0 + r) * K + k0 + kcg * 8)
          : (B + (size_t)(n0 + r - TM) * K + k0 + kcg * 8);
      __builtin_amdgcn_global_load_lds(
          (const __attribute__((address_space(1))) void*)src,
          (__attribute__((address_space(3))) void*)(&s[buf][0] + (size_t)((it << 8) + wbase) * 8),
          16, 0, 0);
    }
  };

  const int NT = K >> 6;
  stage(0, 0);
  stage(1, 64);
  s_wait_vmcnt<GI>();   // buf0 complete; buf1 in flight
  raw_barrier();

  for (int t = 0; t < NT; ++t) {
    if (t + 2 < NT) stage((t + 2) % 3, (t + 2) << 6);

    const unsigned short* sb = &s[t % 3][0];
    const int rl = lane & 15, kq = lane >> 4;
    bf16x8_t af[MI][2], bfr[NI][2];
    #pragma unroll
    for (int mi = 0; mi < MI; ++mi) {
      const int row = wm * (TM / 2) + mi * 16 + rl;
      #pragma unroll
      for (int ks = 0; ks < 2; ++ks) {
        const int ch = row * 8 + ((ks * 4 + kq) ^ (row & 7));
        af[mi][ks] = *(const bf16x8_t*)(sb + (size_t)ch * 8);
      }
    }
    #pragma unroll
    for (int ni = 0; ni < NI; ++ni) {
      const int row = TM + wn * (NC / 2) + ni * 16 + rl;
      #pragma unroll
      for (int ks = 0; ks < 2; ++ks) {
        const int ch = row * 8 + ((ks * 4 + kq) ^ (row & 7));
        bfr[ni][ks] = *(const bf16x8_t*)(sb + (size_t)ch * 8);
      }
    }
    #pragma unroll
    for (int mi = 0; mi < MI; ++mi)
      #pragma unroll
      for (int ni = 0; ni < NI; ++ni)
        #pragma unroll
        for (int ks = 0; ks < 2; ++ks)
          acc[mi][ni] = __builtin_amdgcn_mfma_f32_16x16x32_bf16(
              af[mi][ks], bfr[ni][ks], acc[mi][ni], 0, 0, 0);

    if (t + 1 < NT) {
      if (t + 2 < NT) s_wait_vmcnt<GI>();  // next buf ready, newest stays in flight
      else            s_wait_vmcnt<0>();
      raw_barrier();
    }
  }

  const int rl = lane & 15, rg = lane >> 4;
  #pragma unroll
  for (int mi = 0; mi < MI; ++mi) {
    #pragma unroll
    for (int ni = 0; ni < NI; ++ni) {
      const int col = n0 + wn * (NC / 2) + ni * 16 + rl;
      #pragma unroll
      for (int j = 0; j < 4; ++j) {
        const int row = m0 + wm * (TM / 2) + mi * 16 + rg * 4 + j;
        float v = acc[mi][ni][j];
        if (bias) v += BROW ? bias[row] : bias[col];
        if (ACT == 1) v = silu_f(v);
        else if (ACT == 2) v = softplus_f(v);
        else if (ACT == 3) { if (row >= 1024) v = silu_f(v); }
        else if (ACT == 4) { if (row < 1024)  v = softplus_f(v); }
        if (O32) C32[(size_t)row * N + col] = v;
        if (O16) C16[(size_t)row * N + col] = f2bf(v);
      }
    }
  }
}

// ---------------- chunk-parallel selective scan ----------------
// thread = (d, n); block = 16 d x 16 n; grid = (CCH, DD/16).
// BT/CT are [n][l] (row stride LL) from the combined GEMM output.
__global__ __launch_bounds__(256) void scan_p1(
    const float* __restrict__ deltaT, const float* __restrict__ xcT,
    const float* __restrict__ BT, const float* __restrict__ A_log,
    float* __restrict__ P, float* __restrict__ H)
{
  const int tid = threadIdx.x;
  const int n = tid & 15, dl = tid >> 4;
  const int d = blockIdx.y * 16 + dl;
  const int c = blockIdx.x;
  const int l0 = c * CLEN;
  const float Av = -expf(A_log[d * NS + n]);
  float h = 0.f, p = 1.f;
  for (int j = 0; j < CLEN; j += 4) {
    const float4 dv = *(const float4*)&deltaT[(size_t)d * LL + l0 + j];
    const float4 xv = *(const float4*)&xcT[(size_t)d * LL + l0 + j];
    const float4 bv = *(const float4*)&BT[(size_t)n * LL + l0 + j];
    const float dvu[4] = {dv.x, dv.y, dv.z, dv.w};
    const float xvu[4] = {xv.x, xv.y, xv.z, xv.w};
    const float bvu[4] = {bv.x, bv.y, bv.z, bv.w};
    #pragma unroll
    for (int u = 0; u < 4; ++u) {
      const float ab = expf(dvu[u] * Av);
      h = fmaf(ab, h, dvu[u] * xvu[u] * bvu[u]);
      p *= ab;
    }
  }
  const int idx = d * NS + n;
  P[(size_t)c * (DD * NS) + idx] = p;
  H[(size_t)c * (DD * NS) + idx] = h;
}

__global__ __launch_bounds__(256) void scan_p2(const float* __restrict__ P,
                                               const float* __restrict__ H,
                                               float* __restrict__ Hin) {
  const int idx = blockIdx.x * 256 + threadIdx.x;  // 0..16383
  float hin = 0.f;
  Hin[idx] = 0.f;
  #pragma unroll
  for (int c = 1; c < CCH; ++c) {
    hin = fmaf(P[(size_t)(c - 1) * (DD * NS) + idx], hin,
               H[(size_t)(c - 1) * (DD * NS) + idx]);
    Hin[(size_t)c * (DD * NS) + idx] = hin;
  }
}

__global__ __launch_bounds__(256) void scan_p3(
    const float* __restrict__ deltaT, const float* __restrict__ xcT,
    const float* __restrict__ BT, const float* __restrict__ CT,
    const float* __restrict__ Hin, const float* __restrict__ A_log,
    unsigned short* __restrict__ y16)
{
  const int tid = threadIdx.x;
  const int n = tid & 15, dl = tid >> 4;
  const int d = blockIdx.y * 16 + dl;
  const int c = blockIdx.x;
  const int l0 = c * CLEN;
  const float Av = -expf(A_log[d * NS + n]);
  float h = Hin[(size_t)c * (DD * NS) + d * NS + n];
  for (int j = 0; j < CLEN; j += 4) {
    const float4 dv = *(const float4*)&deltaT[(size_t)d * LL + l0 + j];
    const float4 xv = *(const float4*)&xcT[(size_t)d * LL + l0 + j];
    const float4 bv = *(const float4*)&BT[(size_t)n * LL + l0 + j];
    const float4 cv = *(const float4*)&CT[(size_t)n * LL + l0 + j];
    const float dvu[4] = {dv.x, dv.y, dv.z, dv.w};
    const float xvu[4] = {xv.x, xv.y, xv.z, xv.w};
    const float bvu[4] = {bv.x, bv.y, bv.z, bv.w};
    const float cvu[4] = {cv.x, cv.y, cv.z, cv.w};
    #pragma unroll
    for (int u = 0; u < 4; ++u) {
      const int l = l0 + j + u;
      const float ab = expf(dvu[u] * Av);
      h = fmaf(ab, h, dvu[u] * xvu[u] * bvu[u]);
      float contrib = h * cvu[u];
      contrib += __shfl_xor(contrib, 1);
      contrib += __shfl_xor(contrib, 2);
      contrib += __shfl_xor(contrib, 4);
      contrib += __shfl_xor(contrib, 8);
      if (n == 0) y16[(size_t)l * DD + d] = f2bf(contrib);
    }
  }
}

// ---------------- launch ----------------
extern "C" void kernel_launch(void* const* d_in, const int* in_sizes, int n_in,
                              void* d_out, int out_size, void* d_ws, size_t ws_size,
                              hipStream_t stream) {
  const float* x       = (const float*)d_in[0];
  const float* W_proj  = (const float*)d_in[1];
  const float* b_proj  = (const float*)d_in[2];
  const float* conv_w  = (const float*)d_in[3];
  const float* conv_b  = (const float*)d_in[4];
  const float* A_log   = (const float*)d_in[5];
  const float* W_delta = (const float*)d_in[6];
  const float* W_B     = (const float*)d_in[7];
  const float* W_C     = (const float*)d_in[8];
  float* out = (float*)d_out;

  // Workspace layout (byte offsets), no aliasing, peak 47 MB (ws is 256 MB).
  // Every region fully written before read (0xAA poison harmless; wcomb pad
  // rows are explicitly zeroed).
  char* w = (char*)d_ws;
  const size_t MB = 1024 * 1024;
  unsigned short* x16     = (unsigned short*)(w + 0);        // 4 MB   [2048][1024]
  unsigned short* wp16    = (unsigned short*)(w + 4 * MB);   // 2 MB
  unsigned short* cw16    = (unsigned short*)(w + 6 * MB);   // 6 MB   [1024][3072]
  unsigned short* wcomb16 = (unsigned short*)(w + 12 * MB);  // 2.25MB [1088][1024]
  unsigned short* pbuf    = (unsigned short*)(w + 15 * MB);  // 4 MB:  xm16 | xg16
  unsigned short* xm16    = pbuf;
  unsigned short* xg16    = pbuf + 1024 * 1024;
  unsigned short* xsht    = (unsigned short*)(w + 19 * MB);  // 6 MB   [1024][3072]
  unsigned short* xc16    = (unsigned short*)(w + 25 * MB);  // 2 MB   [l][d]
  float*          xc32    = (float*)(w + 27 * MB);           // 4 MB   [l][d]
  float*          xcT32   = (float*)(w + 31 * MB);           // 4 MB   [d][l]
  float*          dcomb32 = (float*)(w + 35 * MB);           // 4.25MB [1088][1024]
  float*          deltaT32= dcomb32;                         // rows 0..1023
  float*          BT32    = dcomb32 + (size_t)1024 * 1024;   // rows 1024..1039
  float*          CT32    = dcomb32 + (size_t)1040 * 1024;   // rows 1040..1055
  unsigned short* y16     = (unsigned short*)(w + 40 * MB);  // 2 MB   [l][d]
  float*          Pc      = (float*)(w + 42 * MB);           // 1 MB
  float*          Hc      = (float*)(w + 43 * MB);           // 1 MB
  float*          HinC    = (float*)(w + 44 * MB);           // 1 MB
  unsigned short* out116  = (unsigned short*)(w + 45 * MB);  // 2 MB
  (void)ws_size;

  const dim3 blk(256);

  // casts / weight prep
  castk<<<dim3(2048), blk, 0, stream>>>(x, x16, 2 * 1024 * 1024);
  castk<<<dim3(1024), blk, 0, stream>>>(W_proj, wp16, 1024 * 1024);
  castk<<<dim3(3072), blk, 0, stream>>>(conv_w, cw16, 3 * 1024 * 1024);
  tcastk<<<dim3(16, 16), blk, 0, stream>>>(W_delta, wcomb16);        // rows 0..1023
  bct_cast<<<dim3(64), blk, 0, stream>>>(W_B, W_C, wcomb16);         // rows 1024..1087

  // p = x @ W_proj^T + b ; rows<1024 -> xm (no act), rows>=1024 -> xg (silu)
  gemm_bf16<64, 64, 3, false, false, true><<<dim3(16, 32), blk, 0, stream>>>(
      x16, wp16, b_proj, nullptr, pbuf, 2048, 1024, 1024);
  // shifted-transposed conv activations
  build_xsht<<<dim3(16, 16), blk, 0, stream>>>(xm16, xsht);
  // xc = silu(conv(xm) + conv_b): implicit GEMM, K = 3072, row bias
  gemm_bf16<64, 64, 1, true, true, true><<<dim3(16, 16), blk, 0, stream>>>(
      cw16, xsht, conv_b, xc32, xc16, 1024, 1024, 3072);
  // combined: rows 0..1023 deltaT (softplus), 1024..1039 B^T, 1040..1055 C^T
  gemm_bf16<64, 64, 4, false, true, false><<<dim3(16, 17), blk, 0, stream>>>(
      wcomb16, xc16, nullptr, dcomb32, nullptr, 1088, 1024, 1024);
  // xcT for the scan
  transpose_f32<<<dim3(16, 16), blk, 0, stream>>>(xc32, xcT32);
  // chunk-parallel scan
  scan_p1<<<dim3(CCH, DD / 16), blk, 0, stream>>>(deltaT32, xcT32, BT32, A_log, Pc, Hc);
  scan_p2<<<dim3(64), blk, 0, stream>>>(Pc, Hc, HinC);
  scan_p3<<<dim3(CCH, DD / 16), blk, 0, stream>>>(deltaT32, xcT32, BT32, CT32, HinC, A_log, y16);
  // out1 = y @ xg^T
  gemm_bf16<64, 64, 0, false, false, true><<<dim3(16, 16), blk, 0, stream>>>(
      y16, xg16, nullptr, nullptr, out116, 1024, 1024, 1024);
  // out = out1 @ W_proj^T + b
  gemm_bf16<64, 64, 0, false, true, false><<<dim3(16, 16), blk, 0, stream>>>(
      out116, wp16, b_proj, out, nullptr, 1024, 1024, 1024);
}